// Round 2
// baseline (404.118 us; speedup 1.0000x reference)
//
#include <hip/hip_runtime.h>
#include <hip/hip_bf16.h>
#include <stdint.h>

typedef __bf16 bf16;
typedef __bf16 bf16x8 __attribute__((ext_vector_type(8)));
typedef float  f32x4  __attribute__((ext_vector_type(4)));

#define N_B 4
#define N_T 2048
#define N_D 768
#define N_H 12
#define N_DH 64
#define M_TOT (N_B * N_T)   // 8192

// async global->LDS, 16 bytes per lane. LDS dest must be base + lane*16.
__device__ __forceinline__ void async_copy16(const bf16* g, bf16* l) {
    __builtin_amdgcn_global_load_lds(
        (const __attribute__((address_space(1))) unsigned int*)g,
        (__attribute__((address_space(3))) unsigned int*)l,
        16, 0, 0);
}

// fp32 -> bf16 elementwise convert (n % 1024 == 0 for all our calls)
__launch_bounds__(256)
__global__ void f2bf(const float* __restrict__ in, bf16* __restrict__ out, int n) {
    const int i = (blockIdx.x * 256 + threadIdx.x) * 4;
    if (i + 3 < n) {
        const float4 v = *(const float4*)(in + i);
        out[i]     = (bf16)v.x;
        out[i + 1] = (bf16)v.y;
        out[i + 2] = (bf16)v.z;
        out[i + 3] = (bf16)v.w;
    }
}

// ---------------------------------------------------------------------------
// GEMM core: C[m,n] = sum_k A[m,k] * Bt[n,k]  (both K-contiguous, bf16)
// 128x128 tile, BK=32, 256 threads (4 waves, 2x2 of 64x64), 16x16x32 MFMA.
// ---------------------------------------------------------------------------
#define GEMM_CORE(A_PTR, B_PTR, KDIM)                                          \
    __shared__ bf16 lsA[128 * 32];                                             \
    __shared__ bf16 lsB[128 * 32];                                             \
    const int m0 = blockIdx.x * 128;                                           \
    const int n0 = blockIdx.y * 128;                                           \
    const int t  = threadIdx.x;                                                \
    const int w  = t >> 6, l = t & 63;                                         \
    const int wm = w & 1, wn = w >> 1;                                         \
    const int lr = l & 15, lq = l >> 4;                                        \
    f32x4 acc[4][4] = {};                                                      \
    const bf16* Ab = (A_PTR) + (size_t)(m0 + (t >> 2)) * (KDIM) + (t & 3) * 8; \
    const bf16* Bb = (B_PTR) + (size_t)(n0 + (t >> 2)) * (KDIM) + (t & 3) * 8; \
    bf16* lA = lsA + t * 8;                                                    \
    bf16* lB = lsB + t * 8;                                                    \
    for (int k0 = 0; k0 < (KDIM); k0 += 32) {                                  \
        __syncthreads();                                                       \
        async_copy16(Ab + k0, lA);                                             \
        async_copy16(Ab + (size_t)64 * (KDIM) + k0, lA + 2048);                \
        async_copy16(Bb + k0, lB);                                             \
        async_copy16(Bb + (size_t)64 * (KDIM) + k0, lB + 2048);                \
        __syncthreads();                                                       \
        bf16x8 af[4], bfr[4];                                                  \
        for (int i = 0; i < 4; i++) {                                          \
            af[i]  = *(const bf16x8*)(lsA + (wm * 64 + i * 16 + lr) * 32 + lq * 8); \
            bfr[i] = *(const bf16x8*)(lsB + (wn * 64 + i * 16 + lr) * 32 + lq * 8); \
        }                                                                      \
        for (int i = 0; i < 4; i++)                                            \
            for (int j = 0; j < 4; j++)                                        \
                acc[i][j] = __builtin_amdgcn_mfma_f32_16x16x32_bf16(           \
                    af[i], bfr[j], acc[i][j], 0, 0, 0);                        \
    }

// QKV projection: Xb[8192x768] * Wb[2304x768]^T + b_qkv -> Q/K/V [B,H,T,Dh] bf16
__launch_bounds__(256)
__global__ void gemm_qkv(const bf16* __restrict__ X, const bf16* __restrict__ W,
                         const float* __restrict__ bias,
                         bf16* __restrict__ Q, bf16* __restrict__ K,
                         bf16* __restrict__ V) {
    GEMM_CORE(X, W, 768)
    // epilogue: C/D layout col=lane&15, row=(lane>>4)*4+reg
    for (int i = 0; i < 4; i++) {
        const int rowb = m0 + wm * 64 + i * 16 + lq * 4;
        for (int j = 0; j < 4; j++) {
            const int col   = n0 + wn * 64 + j * 16 + lr;
            const int which = col / 768;
            const int rem   = col - which * 768;
            const int h     = rem >> 6, d = rem & 63;
            bf16* dst = (which == 0) ? Q : (which == 1) ? K : V;
            const float bv = bias[col];
            for (int r = 0; r < 4; r++) {
                const int m  = rowb + r;
                const int b_ = m >> 11, tt = m & 2047;
                dst[(size_t)(((b_ * N_H + h) << 11) + tt) * 64 + d] =
                    (bf16)(acc[i][j][r] + bv);
            }
        }
    }
}

// Output projection: Ob[8192x768] * Wpb[768x768]^T + b_proj -> out fp32
__launch_bounds__(256)
__global__ void gemm_proj(const bf16* __restrict__ O, const bf16* __restrict__ W,
                          const float* __restrict__ bias, float* __restrict__ out) {
    GEMM_CORE(O, W, 768)
    for (int i = 0; i < 4; i++) {
        const int rowb = m0 + wm * 64 + i * 16 + lq * 4;
        for (int j = 0; j < 4; j++) {
            const int col  = n0 + wn * 64 + j * 16 + lr;
            const float bv = bias[col];
            for (int r = 0; r < 4; r++)
                out[(size_t)(rowb + r) * 768 + col] = acc[i][j][r] + bv;
        }
    }
}

// ---------------------------------------------------------------------------
// Flash attention: one block per (b*h, 64-row Q tile). 4 waves; wave w owns
// Q rows [16w,16w+16). Iterate 32 K-tiles of 64 keys with online softmax.
// ---------------------------------------------------------------------------
__launch_bounds__(256)
__global__ void attn(const bf16* __restrict__ Q, const bf16* __restrict__ K,
                     const bf16* __restrict__ V, bf16* __restrict__ O) {
    const int bh = blockIdx.y;          // b*12 + h
    const int qt = blockIdx.x;          // 0..31
    const int t = threadIdx.x, w = t >> 6, l = t & 63;
    const int lr = l & 15, lq = l >> 4;
    const bf16* Qh = Q + (size_t)bh * N_T * 64;
    const bf16* Kh = K + (size_t)bh * N_T * 64;
    const bf16* Vh = V + (size_t)bh * N_T * 64;
    const int q0 = qt * 64;

    __shared__ bf16 lsP[4 * 16 * 64];   // per-wave 16x64 P tile (wave-private)
    __shared__ bf16 lsVt[64 * 64];      // transposed V tile: [d][key]

    // Q fragments (held in registers across whole loop)
    bf16x8 qf[2];
    for (int ks = 0; ks < 2; ks++)
        qf[ks] = *(const bf16x8*)(Qh + (size_t)(q0 + w * 16 + lr) * 64 + ks * 32 + lq * 8);

    f32x4 oacc[4] = {};
    float m_i[4], l_i[4];
    for (int r = 0; r < 4; r++) { m_i[r] = -1e30f; l_i[r] = 0.f; }

    for (int kt = 0; kt < 32; kt++) {
        // ---- S = (Q K^T) * scale ----
        f32x4 sacc[4] = {};
        for (int ks = 0; ks < 2; ks++)
            for (int nj = 0; nj < 4; nj++) {
                bf16x8 kf = *(const bf16x8*)(Kh + (size_t)(kt * 64 + nj * 16 + lr) * 64 + ks * 32 + lq * 8);
                sacc[nj] = __builtin_amdgcn_mfma_f32_16x16x32_bf16(qf[ks], kf, sacc[nj], 0, 0, 0);
            }
        for (int nj = 0; nj < 4; nj++)
            for (int r = 0; r < 4; r++) sacc[nj][r] *= 0.125f;

        // ---- row max over this tile (rows live in 16-lane groups) ----
        float pm[4];
        for (int r = 0; r < 4; r++)
            pm[r] = fmaxf(fmaxf(sacc[0][r], sacc[1][r]), fmaxf(sacc[2][r], sacc[3][r]));
        for (int mask = 1; mask < 16; mask <<= 1)
            for (int r = 0; r < 4; r++)
                pm[r] = fmaxf(pm[r], __shfl_xor(pm[r], mask, 64));

        float alpha[4];
        for (int r = 0; r < 4; r++) {
            const float mn = fmaxf(m_i[r], pm[r]);
            alpha[r] = __expf(m_i[r] - mn);
            m_i[r]   = mn;
        }

        // ---- P = exp(S - m), row sums ----
        float rs[4] = {0.f, 0.f, 0.f, 0.f};
        bf16 pb[4][4];
        for (int nj = 0; nj < 4; nj++)
            for (int r = 0; r < 4; r++) {
                const float p = __expf(sacc[nj][r] - m_i[r]);
                rs[r] += p;
                pb[nj][r] = (bf16)p;
            }
        for (int mask = 1; mask < 16; mask <<= 1)
            for (int r = 0; r < 4; r++)
                rs[r] += __shfl_xor(rs[r], mask, 64);
        for (int r = 0; r < 4; r++)
            l_i[r] = l_i[r] * alpha[r] + rs[r];

        // ---- P to LDS (C-layout -> A-layout round trip), rescale O ----
        for (int nj = 0; nj < 4; nj++)
            for (int r = 0; r < 4; r++)
                lsP[w * 1024 + (lq * 4 + r) * 64 + nj * 16 + lr] = pb[nj][r];
        for (int dj = 0; dj < 4; dj++)
            for (int r = 0; r < 4; r++) oacc[dj][r] *= alpha[r];

        __syncthreads();   // previous iteration's lsVt reads are done
        {   // stage V^T: thread handles key row t/4, 16 d-cols starting (t&3)*16
            const int row = t >> 2, c0 = (t & 3) << 4;
            const bf16* vsrc = Vh + (size_t)(kt * 64 + row) * 64 + c0;
            bf16x8 v0 = *(const bf16x8*)(vsrc);
            bf16x8 v1 = *(const bf16x8*)(vsrc + 8);
            for (int j = 0; j < 8; j++) {
                lsVt[(c0 + j) * 64 + row]     = v0[j];
                lsVt[(c0 + 8 + j) * 64 + row] = v1[j];
            }
        }
        __syncthreads();   // lsVt (and lsP) visible

        // ---- O += P V ----
        for (int ks = 0; ks < 2; ks++) {
            bf16x8 pf = *(const bf16x8*)(lsP + w * 1024 + lr * 64 + ks * 32 + lq * 8);
            for (int dj = 0; dj < 4; dj++) {
                bf16x8 vf = *(const bf16x8*)(lsVt + (dj * 16 + lr) * 64 + ks * 32 + lq * 8);
                oacc[dj] = __builtin_amdgcn_mfma_f32_16x16x32_bf16(pf, vf, oacc[dj], 0, 0, 0);
            }
        }
    }

    // ---- epilogue: O / l_i -> [B,T,D] bf16 ----
    const int b = bh / N_H, h = bh - b * N_H;
    bf16* Ob = O + ((size_t)b * N_T + q0 + w * 16) * N_D + h * 64;
    for (int dj = 0; dj < 4; dj++)
        for (int r = 0; r < 4; r++) {
            const int m = lq * 4 + r;
            const int d = dj * 16 + lr;
            Ob[(size_t)m * N_D + d] = (bf16)(oacc[dj][r] / l_i[r]);
        }
}

extern "C" void kernel_launch(void* const* d_in, const int* in_sizes, int n_in,
                              void* d_out, int out_size, void* d_ws, size_t ws_size,
                              hipStream_t stream) {
    const float* x      = (const float*)d_in[0];
    const float* W_qkv  = (const float*)d_in[1];
    const float* b_qkv  = (const float*)d_in[2];
    const float* W_proj = (const float*)d_in[3];
    const float* b_proj = (const float*)d_in[4];
    float* out = (float*)d_out;

    char* ws = (char*)d_ws;
    const size_t n_x  = (size_t)M_TOT * N_D;        // 6291456
    const size_t n_wq = (size_t)3 * N_D * N_D;      // 1769472
    const size_t n_wp = (size_t)N_D * N_D;          // 589824
    const size_t sz_qkv = (size_t)N_B * N_H * N_T * N_DH * sizeof(bf16);  // 12.58 MB

    bf16* xb  = (bf16*)(ws);                 ws += n_x * sizeof(bf16);
    bf16* Wqb = (bf16*)(ws);                 ws += n_wq * sizeof(bf16);
    bf16* Wpb = (bf16*)(ws);                 ws += n_wp * sizeof(bf16);
    bf16* Qb  = (bf16*)(ws);                 ws += sz_qkv;
    bf16* Kb  = (bf16*)(ws);                 ws += sz_qkv;
    bf16* Vb  = (bf16*)(ws);                 ws += sz_qkv;
    bf16* Ob  = (bf16*)(ws);

    dim3 blk(256);
    f2bf<<<dim3((int)(n_x  / 1024)), blk, 0, stream>>>(x,      xb,  (int)n_x);
    f2bf<<<dim3((int)(n_wq / 1024)), blk, 0, stream>>>(W_qkv,  Wqb, (int)n_wq);
    f2bf<<<dim3((int)(n_wp / 1024)), blk, 0, stream>>>(W_proj, Wpb, (int)n_wp);

    gemm_qkv<<<dim3(M_TOT / 128, 2304 / 128), blk, 0, stream>>>(xb, Wqb, b_qkv, Qb, Kb, Vb);
    attn<<<dim3(N_T / 64, N_B * N_H), blk, 0, stream>>>(Qb, Kb, Vb, Ob);
    gemm_proj<<<dim3(M_TOT / 128, 768 / 128), blk, 0, stream>>>(Ob, Wpb, b_proj, out);
}